// Round 4
// baseline (665.306 us; speedup 1.0000x reference)
//
#include <hip/hip_runtime.h>
#include <hip/hip_bf16.h>

// Problem constants (fixed by reference file)
#define EMBED    256
#define HEADS    8
#define LEVELS   4
#define POINTS   4
#define HEAD_DIM 32
#define BS       8
#define NQ       900
#define NV       13294          // 100*100 + 50*50 + 25*25 + 13*13
#define MV       (BS*NV)        // 106352 rows of the value GEMM (= 6647*16)
#define MQ       (BS*NQ)        // 7200 rows of the query GEMMs  (= 450*16)
#define NQOUT    384            // 256 offset cols + 128 attn cols

typedef float  f32x4  __attribute__((ext_vector_type(4)));
typedef __bf16 bf16x8 __attribute__((ext_vector_type(8)));
typedef unsigned short ushort8  __attribute__((ext_vector_type(8)));
typedef unsigned short ushort4v __attribute__((ext_vector_type(4)));

__device__ __forceinline__ unsigned short f2bf(float f) {
    unsigned u = __builtin_bit_cast(unsigned, f);
    u += 0x7FFFu + ((u >> 16) & 1u);          // RNE
    return (unsigned short)(u >> 16);
}
__device__ __forceinline__ float bf2f(unsigned short h) {
    unsigned u = ((unsigned)h) << 16;
    return __builtin_bit_cast(float, u);
}

// ---------------------------------------------------------------------------
// Prep: transpose + cast weights to bf16 (B^T layout: [n][k], k contiguous)
// ---------------------------------------------------------------------------
__global__ __launch_bounds__(256) void prep_kernel(
    const float* __restrict__ Wv,  const float* __restrict__ Woff,
    const float* __restrict__ Wattn, const float* __restrict__ Wout,
    const float* __restrict__ boff, const float* __restrict__ battn,
    unsigned short* __restrict__ WtV, unsigned short* __restrict__ WtQ,
    unsigned short* __restrict__ WtO, float* __restrict__ biasQ)
{
    int n = blockIdx.x;      // 0..383
    int k = threadIdx.x;     // 0..255
    if (n < 256) {
        WtV[n * 256 + k] = f2bf(Wv [k * 256 + n]);
        WtO[n * 256 + k] = f2bf(Wout[k * 256 + n]);
        WtQ[n * 256 + k] = f2bf(Woff[k * 256 + n]);
    } else {
        int j = n - 256;
        WtQ[n * 256 + k] = f2bf(Wattn[k * 128 + j]);
    }
    if (k == 0) biasQ[n] = (n < 256) ? boff[n] : battn[n - 256];
}

// ---------------------------------------------------------------------------
// Streaming GEMM, K=256: weight slice (NT*16 x 256 bf16) in LDS, loaded once
// (one barrier); each wave independently streams 16-row strips of A with a
// DEPTH-4 rotating load pipeline (8 f32x4 = 32 VGPRs in flight, loads issued
// 4 k-chunks ahead). MFMA operands swapped (weights = A-op, value rows =
// B-op) so each lane's 4 acc regs are 4 consecutive output columns.
// amdgpu_waves_per_eu(2,2): LDS caps us at 1 block/CU (8 waves = 2/EU), so
// pinning 2 waves/EU gives the allocator the full 256-VGPR budget -> no
// spills (round-3 failure mode: compiler capped at 128 VGPR and spilled).
// ---------------------------------------------------------------------------
#define LDKB 264   // LDS row stride in ushorts (256 + 8; rows 16B-aligned,
                   // row stride 132 dwords == 4 mod 32 -> only 2-way banks)

template <int NT, bool OUT_BF16, bool ADD_ID>
__global__ __launch_bounds__(512) __attribute__((amdgpu_waves_per_eu(2, 2)))
void gemm_stream(
    const float* __restrict__ A,
    const unsigned short* __restrict__ BtBase,   // [Ntot][256] bf16
    const float* __restrict__ biasBase,          // [Ntot]
    const float* __restrict__ Ident,             // [M][Ntot] or null
    void* __restrict__ Cv, int Ntot, int M)
{
    const int n0 = blockIdx.y * (NT * 16);
    const unsigned short* Bt = BtBase + (size_t)n0 * 256;
    const float* bias = biasBase + n0;

    __shared__ unsigned short Bs[NT * 16 * LDKB];
    const int tid = threadIdx.x;
    #pragma unroll
    for (int i = 0; i < NT; ++i) {               // NT*512 ushort8 vectors total
        int flat = (i * 512 + tid) * 8;
        int row = flat >> 8, k0 = flat & 255;
        *(ushort8*)&Bs[row * LDKB + k0] = *(const ushort8*)(Bt + flat);
    }
    __syncthreads();                             // the only barrier

    const int wave = tid >> 6, lane = tid & 63;
    const int lrow = lane & 15, kq = lane >> 4;
    const int stride = gridDim.x * 8;
    const int NS = M / 16;

    for (int s = blockIdx.x * 8 + wave; s < NS; s += stride) {
        const int m0 = s * 16;
        const float* abase = A + (size_t)(m0 + lrow) * 256 + kq * 8;

        // depth-4 rotating pipeline: chunks c..c+3 in flight
        f32x4 pa[4], pb[4];
        #pragma unroll
        for (int c = 0; c < 4; ++c) {
            pa[c] = *(const f32x4*)(abase + c * 32);
            pb[c] = *(const f32x4*)(abase + c * 32 + 4);
        }
        f32x4 acc[NT];
        #pragma unroll
        for (int j = 0; j < NT; ++j) acc[j] = (f32x4)0.f;

        #pragma unroll
        for (int c = 0; c < 8; ++c) {
            ushort8 vb;
            #pragma unroll
            for (int e = 0; e < 4; ++e) {
                vb[e]     = f2bf(pa[c & 3][e]);
                vb[4 + e] = f2bf(pb[c & 3][e]);
            }
            if (c + 4 < 8) {                     // refill the slot 4 ahead
                pa[c & 3] = *(const f32x4*)(abase + (c + 4) * 32);
                pb[c & 3] = *(const f32x4*)(abase + (c + 4) * 32 + 4);
            }
            bf16x8 vfrag = __builtin_bit_cast(bf16x8, vb);
            #pragma unroll
            for (int j = 0; j < NT; ++j) {
                bf16x8 wfrag = *(const bf16x8*)&Bs[(j * 16 + lrow) * LDKB + c * 32 + kq * 8];
                // D[channel = kq*4+reg][value-row = lane&15]
                acc[j] = __builtin_amdgcn_mfma_f32_16x16x32_bf16(wfrag, vfrag, acc[j], 0, 0, 0);
            }
        }

        const size_t crow = (size_t)(m0 + lrow) * Ntot + n0 + kq * 4;
        #pragma unroll
        for (int j = 0; j < NT; ++j) {
            f32x4 r = acc[j] + *(const f32x4*)(bias + j * 16 + kq * 4);
            if (ADD_ID)
                r += *(const f32x4*)(Ident + (size_t)(m0 + lrow) * Ntot + n0 + j * 16 + kq * 4);
            if (OUT_BF16) {
                ushort4v o;
                #pragma unroll
                for (int e = 0; e < 4; ++e) o[e] = f2bf(r[e]);
                *(ushort4v*)((unsigned short*)Cv + crow + j * 16) = o;
            } else {
                *(f32x4*)((float*)Cv + crow + j * 16) = r;
            }
        }
    }
}

// ---------------------------------------------------------------------------
// Sampling: 16 lanes per (b,q,h) triple; lane s (0..15) owns sample s=l*4+p.
// ---------------------------------------------------------------------------
__device__ const int   LVL_W[4]  = {100, 50, 25, 13};
__device__ const int   LVL_H[4]  = {100, 50, 25, 13};
__device__ const int   LVL_S[4]  = {0, 10000, 12500, 13125};

__global__ __launch_bounds__(256) void sample_kernel(
    const unsigned short* __restrict__ V,   // (BS*NV, 256) bf16
    const float* __restrict__ Qout,         // (BS*NQ, 384)
    const float* __restrict__ RP,           // (BS, NQ, 4, 2)
    float* __restrict__ OutS)               // (BS*NQ, 256)
{
    const int gid = blockIdx.x * 16 + (threadIdx.x >> 4);   // triple index
    const int s   = threadIdx.x & 15;                       // lane-in-group
    const int h   = gid & 7;
    const int bq  = gid >> 3;                               // b*NQ + q
    const int b   = bq / NQ;

    const float* qrow = Qout + (size_t)bq * NQOUT;

    const int l = s >> 2;
    const float ox = qrow[h * 32 + 2 * s];
    const float oy = qrow[h * 32 + 2 * s + 1];
    float logit    = qrow[256 + h * 16 + s];
    const float rpx = RP[((size_t)bq * 4 + l) * 2 + 0];
    const float rpy = RP[((size_t)bq * 4 + l) * 2 + 1];
    int W = LVL_W[l], H = LVL_H[l], st = LVL_S[l];
    float x = rpx * (float)W + ox - 0.5f;
    float y = rpy * (float)H + oy - 0.5f;
    float fx = floorf(x), fy = floorf(y);
    float lx = x - fx, ly = y - fy;
    int ix = (int)fx, iy = (int)fy;

    // softmax over the 16 lanes of this group
    float mx = logit;
    #pragma unroll
    for (int o = 8; o; o >>= 1) mx = fmaxf(mx, __shfl_xor(mx, o, 16));
    float e = __expf(logit - mx);
    float sum = e;
    #pragma unroll
    for (int o = 8; o; o >>= 1) sum += __shfl_xor(sum, o, 16);
    const float wgt = e / sum;

    const unsigned short* vb = V + ((size_t)b * NV) * 256 + h * 32 + 2 * s;
    float ax = 0.f, ay = 0.f;

    #pragma unroll
    for (int sp = 0; sp < 16; ++sp) {
        float ws  = __shfl(wgt, sp, 16);
        float lxs = __shfl(lx,  sp, 16);
        float lys = __shfl(ly,  sp, 16);
        int  ixs  = __shfl(ix,  sp, 16);
        int  iys  = __shfl(iy,  sp, 16);
        int  Ws   = __shfl(W,   sp, 16);
        int  Hs   = __shfl(H,   sp, 16);
        int  sts  = __shfl(st,  sp, 16);
        #pragma unroll
        for (int corner = 0; corner < 4; ++corner) {
            int dx = corner & 1, dy = corner >> 1;
            int xi = ixs + dx, yi = iys + dy;
            float cw = ws * (dx ? lxs : 1.f - lxs) * (dy ? lys : 1.f - lys);
            if (xi >= 0 && xi < Ws && yi >= 0 && yi < Hs && cw != 0.f) {
                const unsigned short* p = vb + (size_t)(sts + yi * Ws + xi) * 256;
                unsigned pv = *(const unsigned*)p;       // 2 bf16
                ax += cw * bf2f((unsigned short)(pv & 0xFFFF));
                ay += cw * bf2f((unsigned short)(pv >> 16));
            }
        }
    }
    float2* o = (float2*)(OutS + (size_t)bq * 256 + h * 32);
    o[s] = make_float2(ax, ay);
}

// ---------------------------------------------------------------------------
extern "C" void kernel_launch(void* const* d_in, const int* in_sizes, int n_in,
                              void* d_out, int out_size, void* d_ws, size_t ws_size,
                              hipStream_t stream)
{
    const float* query  = (const float*)d_in[0];
    const float* value  = (const float*)d_in[1];
    const float* rp     = (const float*)d_in[2];
    // d_in[3] spatial_shapes: static, hardcoded
    const float* W_off  = (const float*)d_in[4];
    const float* b_off  = (const float*)d_in[5];
    const float* W_attn = (const float*)d_in[6];
    const float* b_attn = (const float*)d_in[7];
    const float* W_v    = (const float*)d_in[8];
    const float* b_v    = (const float*)d_in[9];
    const float* W_out  = (const float*)d_in[10];
    const float* b_out  = (const float*)d_in[11];

    char* ws = (char*)d_ws;
    size_t off = 0;
    unsigned short* Vbf = (unsigned short*)(ws + off); off += (size_t)MV * 256 * 2;
    float* qout         = (float*)(ws + off);          off += (size_t)MQ * NQOUT * 4;
    float* outs         = (float*)(ws + off);          off += (size_t)MQ * 256 * 4;
    unsigned short* WtV = (unsigned short*)(ws + off); off += 256 * 256 * 2;
    unsigned short* WtQ = (unsigned short*)(ws + off); off += 384 * 256 * 2;
    unsigned short* WtO = (unsigned short*)(ws + off); off += 256 * 256 * 2;
    float* biasQ        = (float*)(ws + off);          off += 384 * 4;

    prep_kernel<<<384, 256, 0, stream>>>(W_v, W_off, W_attn, W_out, b_off, b_attn,
                                         WtV, WtQ, WtO, biasQ);

    // v = value @ W_v + b_v -> bf16.  256 blocks (1/CU), 2048 waves.
    gemm_stream<16, true, false><<<dim3(256, 1), 512, 0, stream>>>(
        value, WtV, b_v, nullptr, Vbf, 256, MV);

    // [off | attn-logits] = query @ [W_off | W_attn] + bias (two 192-col halves)
    gemm_stream<12, false, false><<<dim3(29, 2), 512, 0, stream>>>(
        query, WtQ, biasQ, nullptr, qout, NQOUT, MQ);

    sample_kernel<<<(BS * NQ * HEADS) / 16, 256, 0, stream>>>(Vbf, qout, rp, outs);

    // out = out_s @ W_out + b_out + query
    gemm_stream<16, false, true><<<dim3(57, 1), 512, 0, stream>>>(
        outs, WtO, b_out, query, (float*)d_out, 256, MQ);
}

// Round 5
// 308.825 us; speedup vs baseline: 2.1543x; 2.1543x over previous
//
#include <hip/hip_runtime.h>
#include <hip/hip_bf16.h>

// Problem constants (fixed by reference file)
#define EMBED    256
#define HEADS    8
#define LEVELS   4
#define POINTS   4
#define HEAD_DIM 32
#define BS       8
#define NQ       900
#define NV       13294          // 100*100 + 50*50 + 25*25 + 13*13
#define MV       (BS*NV)        // 106352 = 6647*16
#define MQ       (BS*NQ)        // 7200   = 450*16
#define NQOUT    384            // 256 offset cols + 128 attn cols

typedef float  f32x4  __attribute__((ext_vector_type(4)));
typedef __bf16 bf16x8 __attribute__((ext_vector_type(8)));
typedef unsigned short ushort8  __attribute__((ext_vector_type(8)));
typedef unsigned short ushort4v __attribute__((ext_vector_type(4)));

__device__ __forceinline__ unsigned short f2bf(float f) {
    unsigned u = __builtin_bit_cast(unsigned, f);
    u += 0x7FFFu + ((u >> 16) & 1u);          // RNE
    return (unsigned short)(u >> 16);
}
__device__ __forceinline__ float bf2f(unsigned short h) {
    unsigned u = ((unsigned)h) << 16;
    return __builtin_bit_cast(float, u);
}

// ---------------------------------------------------------------------------
// Prep: transpose + cast weights to bf16 (B^T layout: [n][k], k contiguous)
// ---------------------------------------------------------------------------
__global__ __launch_bounds__(256) void prep_kernel(
    const float* __restrict__ Wv,  const float* __restrict__ Woff,
    const float* __restrict__ Wattn, const float* __restrict__ Wout,
    const float* __restrict__ boff, const float* __restrict__ battn,
    unsigned short* __restrict__ WtV, unsigned short* __restrict__ WtQ,
    unsigned short* __restrict__ WtO, float* __restrict__ biasQ)
{
    int n = blockIdx.x;      // 0..383
    int k = threadIdx.x;     // 0..255
    if (n < 256) {
        WtV[n * 256 + k] = f2bf(Wv [k * 256 + n]);
        WtO[n * 256 + k] = f2bf(Wout[k * 256 + n]);
        WtQ[n * 256 + k] = f2bf(Woff[k * 256 + n]);
    } else {
        int j = n - 256;
        WtQ[n * 256 + k] = f2bf(Wattn[k * 128 + j]);
    }
    if (k == 0) biasQ[n] = (n < 256) ? boff[n] : battn[n - 256];
}

// ---------------------------------------------------------------------------
// Register-resident-weight streaming GEMM (K=256, N = WPB*64).
// Each wave owns a 64-column slice; its weight slice (64x256 bf16) lives in
// 128 VGPRs, loaded ONCE. No LDS, no barriers, no ds_read in the hot loop.
// Hot loop per 16-row strip: 16 global f32x4 loads -> cvt -> 32 MFMA -> store.
// Worst-case allocator behavior = wf reloads from L2 (weights are L2-hot),
// NOT scratch round-trips of the A stream (rounds 3/4 failure mode).
//   C[M x N] = A[M x 256](fp32) * Bt[n][k]^T + bias (+ Ident)
// MFMA operands swapped (weights = A-op): lane's 4 acc regs are 4 consecutive
// output columns. Layout verified by rounds 1-4 passing.
// ---------------------------------------------------------------------------
template <int WPB, bool OUT_BF16, bool ADD_ID>
__global__ __launch_bounds__(WPB * 64, 1)
void gemm_regw(const float* __restrict__ A,
               const unsigned short* __restrict__ Bt,   // [WPB*64][256] bf16
               const float* __restrict__ bias,          // [WPB*64]
               const float* __restrict__ Ident,         // [M][WPB*64] or null
               void* __restrict__ Cv, int M)
{
    constexpr int N = WPB * 64;
    const int tid  = threadIdx.x;
    const int wave = tid >> 6, lane = tid & 63;
    const int lrow = lane & 15, kq = lane >> 4;
    const int n0   = wave * 64;                 // wave's column block

    // ---- weights resident in registers: 32 bf16x8 = 128 VGPRs ----
    bf16x8 wf[4][8];
    #pragma unroll
    for (int j = 0; j < 4; ++j)
        #pragma unroll
        for (int c = 0; c < 8; ++c)
            wf[j][c] = *(const bf16x8*)(Bt + (size_t)(n0 + j * 16 + lrow) * 256
                                           + c * 32 + kq * 8);
    // ---- bias, loop-invariant: 4 f32x4 ----
    f32x4 bj[4];
    #pragma unroll
    for (int j = 0; j < 4; ++j)
        bj[j] = *(const f32x4*)(bias + n0 + j * 16 + kq * 4);

    const int NS    = M / 16;                   // M divisible by 16
    const int chunk = (NS + gridDim.x - 1) / gridDim.x;
    const int sbeg  = blockIdx.x * chunk;
    const int send  = min(NS, sbeg + chunk);

    for (int s = sbeg; s < send; ++s) {
        const float* abase = A + (size_t)(s * 16 + lrow) * 256 + kq * 8;
        f32x4 pa[16];
        #pragma unroll
        for (int c = 0; c < 8; ++c) {
            pa[2 * c]     = *(const f32x4*)(abase + c * 32);
            pa[2 * c + 1] = *(const f32x4*)(abase + c * 32 + 4);
        }
        f32x4 acc[4];
        #pragma unroll
        for (int j = 0; j < 4; ++j) acc[j] = (f32x4)0.f;

        #pragma unroll
        for (int c = 0; c < 8; ++c) {
            ushort8 vb;
            #pragma unroll
            for (int e = 0; e < 4; ++e) {
                vb[e]     = f2bf(pa[2 * c][e]);
                vb[4 + e] = f2bf(pa[2 * c + 1][e]);
            }
            bf16x8 vf = __builtin_bit_cast(bf16x8, vb);
            #pragma unroll
            for (int j = 0; j < 4; ++j)
                acc[j] = __builtin_amdgcn_mfma_f32_16x16x32_bf16(
                    wf[j][c], vf, acc[j], 0, 0, 0);
        }

        const size_t crow = (size_t)(s * 16 + lrow) * N + n0 + kq * 4;
        #pragma unroll
        for (int j = 0; j < 4; ++j) {
            f32x4 r = acc[j] + bj[j];
            if (ADD_ID)
                r += *(const f32x4*)(Ident + crow + j * 16);
            if (OUT_BF16) {
                ushort4v o;
                #pragma unroll
                for (int e = 0; e < 4; ++e) o[e] = f2bf(r[e]);
                *(ushort4v*)((unsigned short*)Cv + crow + j * 16) = o;
            } else {
                *(f32x4*)((float*)Cv + crow + j * 16) = r;
            }
        }
    }
}

// ---------------------------------------------------------------------------
// Sampling: 16 lanes per (b,q,h) triple; lane s (0..15) owns sample s=l*4+p.
// ---------------------------------------------------------------------------
__device__ const int   LVL_W[4]  = {100, 50, 25, 13};
__device__ const int   LVL_H[4]  = {100, 50, 25, 13};
__device__ const int   LVL_S[4]  = {0, 10000, 12500, 13125};

__global__ __launch_bounds__(256) void sample_kernel(
    const unsigned short* __restrict__ V,   // (BS*NV, 256) bf16
    const float* __restrict__ Qout,         // (BS*NQ, 384)
    const float* __restrict__ RP,           // (BS, NQ, 4, 2)
    float* __restrict__ OutS)               // (BS*NQ, 256)
{
    const int gid = blockIdx.x * 16 + (threadIdx.x >> 4);   // triple index
    const int s   = threadIdx.x & 15;                       // lane-in-group
    const int h   = gid & 7;
    const int bq  = gid >> 3;                               // b*NQ + q
    const int b   = bq / NQ;

    const float* qrow = Qout + (size_t)bq * NQOUT;

    const int l = s >> 2;
    const float ox = qrow[h * 32 + 2 * s];
    const float oy = qrow[h * 32 + 2 * s + 1];
    float logit    = qrow[256 + h * 16 + s];
    const float rpx = RP[((size_t)bq * 4 + l) * 2 + 0];
    const float rpy = RP[((size_t)bq * 4 + l) * 2 + 1];
    int W = LVL_W[l], H = LVL_H[l], st = LVL_S[l];
    float x = rpx * (float)W + ox - 0.5f;
    float y = rpy * (float)H + oy - 0.5f;
    float fx = floorf(x), fy = floorf(y);
    float lx = x - fx, ly = y - fy;
    int ix = (int)fx, iy = (int)fy;

    // softmax over the 16 lanes of this group
    float mx = logit;
    #pragma unroll
    for (int o = 8; o; o >>= 1) mx = fmaxf(mx, __shfl_xor(mx, o, 16));
    float e = __expf(logit - mx);
    float sum = e;
    #pragma unroll
    for (int o = 8; o; o >>= 1) sum += __shfl_xor(sum, o, 16);
    const float wgt = e / sum;

    const unsigned short* vb = V + ((size_t)b * NV) * 256 + h * 32 + 2 * s;
    float ax = 0.f, ay = 0.f;

    #pragma unroll
    for (int sp = 0; sp < 16; ++sp) {
        float ws  = __shfl(wgt, sp, 16);
        float lxs = __shfl(lx,  sp, 16);
        float lys = __shfl(ly,  sp, 16);
        int  ixs  = __shfl(ix,  sp, 16);
        int  iys  = __shfl(iy,  sp, 16);
        int  Ws   = __shfl(W,   sp, 16);
        int  Hs   = __shfl(H,   sp, 16);
        int  sts  = __shfl(st,  sp, 16);
        #pragma unroll
        for (int corner = 0; corner < 4; ++corner) {
            int dx = corner & 1, dy = corner >> 1;
            int xi = ixs + dx, yi = iys + dy;
            float cw = ws * (dx ? lxs : 1.f - lxs) * (dy ? lys : 1.f - lys);
            if (xi >= 0 && xi < Ws && yi >= 0 && yi < Hs && cw != 0.f) {
                const unsigned short* p = vb + (size_t)(sts + yi * Ws + xi) * 256;
                unsigned pv = *(const unsigned*)p;       // 2 bf16
                ax += cw * bf2f((unsigned short)(pv & 0xFFFF));
                ay += cw * bf2f((unsigned short)(pv >> 16));
            }
        }
    }
    float2* o = (float2*)(OutS + (size_t)bq * 256 + h * 32);
    o[s] = make_float2(ax, ay);
}

// ---------------------------------------------------------------------------
extern "C" void kernel_launch(void* const* d_in, const int* in_sizes, int n_in,
                              void* d_out, int out_size, void* d_ws, size_t ws_size,
                              hipStream_t stream)
{
    const float* query  = (const float*)d_in[0];
    const float* value  = (const float*)d_in[1];
    const float* rp     = (const float*)d_in[2];
    // d_in[3] spatial_shapes: static, hardcoded
    const float* W_off  = (const float*)d_in[4];
    const float* b_off  = (const float*)d_in[5];
    const float* W_attn = (const float*)d_in[6];
    const float* b_attn = (const float*)d_in[7];
    const float* W_v    = (const float*)d_in[8];
    const float* b_v    = (const float*)d_in[9];
    const float* W_out  = (const float*)d_in[10];
    const float* b_out  = (const float*)d_in[11];

    char* ws = (char*)d_ws;
    size_t off = 0;
    unsigned short* Vbf = (unsigned short*)(ws + off); off += (size_t)MV * 256 * 2;
    float* qout         = (float*)(ws + off);          off += (size_t)MQ * NQOUT * 4;
    float* outs         = (float*)(ws + off);          off += (size_t)MQ * 256 * 4;
    unsigned short* WtV = (unsigned short*)(ws + off); off += 256 * 256 * 2;
    unsigned short* WtQ = (unsigned short*)(ws + off); off += 384 * 256 * 2;
    unsigned short* WtO = (unsigned short*)(ws + off); off += 256 * 256 * 2;
    float* biasQ        = (float*)(ws + off);          off += 384 * 4;

    prep_kernel<<<384, 256, 0, stream>>>(W_v, W_off, W_attn, W_out, b_off, b_attn,
                                         WtV, WtQ, WtO, biasQ);

    // v = value @ W_v + b_v -> bf16.  512 blocks x 4 waves, ~13 strips each.
    gemm_regw<4, true, false><<<512, 256, 0, stream>>>(
        value, WtV, b_v, nullptr, Vbf, MV);

    // [off | attn-logits] = query @ [W_off | W_attn] + bias (384 cols, 6 waves)
    gemm_regw<6, false, false><<<225, 384, 0, stream>>>(
        query, WtQ, biasQ, nullptr, qout, MQ);

    sample_kernel<<<(BS * NQ * HEADS) / 16, 256, 0, stream>>>(Vbf, qout, rp, outs);

    // out = out_s @ W_out + b_out + query
    gemm_regw<4, false, true><<<225, 256, 0, stream>>>(
        outs, WtO, b_out, query, (float*)d_out, MQ);
}